// Round 23
// baseline (2059.335 us; speedup 1.0000x reference)
//
#include <hip/hip_runtime.h>
#include <hip/hip_bf16.h>

#define NP 131072
#define D 128
#define KC 2048
#define ITERS 5
#define CG 8           // clusters per accum block

#define TAU 0.015f     // bf16x3 top-2 gap below which we recheck in f64
#define CNOFF 49152    // LDS byte offset of the 512B cnorm slot

#if defined(__has_builtin)
#if __has_builtin(__builtin_amdgcn_global_load_lds)
#define USE_GLL 1
#endif
#endif

typedef short bf16x8 __attribute__((ext_vector_type(8)));
typedef float f32x16 __attribute__((ext_vector_type(16)));

__device__ inline unsigned short f2bf(float x) {
    __hip_bfloat16 b = __float2bfloat16(x);
    return *reinterpret_cast<unsigned short*>(&b);
}
__device__ inline float bf2f(unsigned short u) {
    union { unsigned int i; float f; } c; c.i = ((unsigned int)u) << 16; return c.f;
}

// 32x32x16 fragment-major panel: for cluster k, dim d, half hl:
//   ct=k>>7, kc=k&127, g2=kc>>5 (32-col tile), c32=kc&31
//   ks32=d>>5 (32-k step), sub=(d>>4)&1 (16-k sub), kk=d&15
//   frag lane = (kk>>3)*32 + c32, e = kk&7
//   frag index f = sub*8 + g2*2 + hl  (16 frags x 1KB = 16KB chunk)
//   ushort idx = (ks32*128 + ct*8)*1024 + f*512 + lane*8 + e
// Chunk addressing identical to the 16x16 panel -> staging code unchanged.
__device__ inline size_t pslot(int k, int d, int hl) {
    int ct = k >> 7, kc = k & 127, g2 = kc >> 5, c32 = kc & 31;
    int ks32 = d >> 5, sub = (d >> 4) & 1, kk = d & 15;
    int lane = (kk >> 3) * 32 + c32, e = kk & 7;
    int f = sub * 8 + g2 * 2 + hl;
    return ((size_t)(ks32 * 128 + ct * 8)) * 1024 + f * 512 + lane * 8 + e;
}

#if USE_GLL
#define GLL16(srcp, dstp) __builtin_amdgcn_global_load_lds( \
    (const __attribute__((address_space(1))) unsigned int*)(srcp), \
    (__attribute__((address_space(3))) unsigned int*)(dstp), 16, 0, 0)
#define GLL4(srcp, dstp) __builtin_amdgcn_global_load_lds( \
    (const __attribute__((address_space(1))) unsigned int*)(srcp), \
    (__attribute__((address_space(3))) unsigned int*)(dstp), 4, 0, 0)
#else
#define GLL16(srcp, dstp) do { *(uint4*)((char*)(dstp) + lane * 16) = *(const uint4*)(srcp); } while (0)
#define GLL4(srcp, dstp)  do { *(unsigned int*)((char*)(dstp) + lane * 4) = *(const unsigned int*)(srcp); } while (0)
#endif

// ---------------------------------------------------------------------------
// init: C64 / CT64 / panel + fused cnorm + counter reset for iteration 0
// ---------------------------------------------------------------------------
__global__ void init_kernel(const float* __restrict__ initC,
                            double* __restrict__ C64, double* __restrict__ CT64,
                            unsigned short* __restrict__ Pn,
                            double* __restrict__ cn64, float* __restrict__ cn32,
                            int* __restrict__ counter) {
    __shared__ double sred[4];
    int tid = threadIdx.x;
    int t = blockIdx.x * 256 + tid;       // 262144
    float v = initC[t];
    double dv = (double)v;
    C64[t] = dv;
    CT64[(size_t)(t & 127) * KC + (t >> 7)] = dv;
    unsigned short h = f2bf(v);
    int k = t >> 7, d = t & 127;
    Pn[pslot(k, d, 0)] = h;
    Pn[pslot(k, d, 1)] = f2bf(v - bf2f(h));
    double s = dv * dv;
#pragma unroll
    for (int m = 1; m < 64; m <<= 1) s += __shfl_xor(s, m, 64);
    if ((tid & 63) == 0) sred[tid >> 6] = s;
    __syncthreads();
    if (tid == 0)   { double ss = sred[0] + sred[1]; cn64[k] = ss; cn32[k] = (float)ss; }
    if (tid == 128) { double ss = sred[2] + sred[3]; cn64[k] = ss; cn32[k] = (float)ss; }
    if (blockIdx.x == 0 && tid == 0) *counter = 0;
}

// ---------------------------------------------------------------------------
// bf16x3 MFMA assign — R23: 32x32x16 MFMA (48 instr/ct vs 96), same 4-wave
// BM=64 counted-vmcnt 3-deep pipeline, same staging/vmcnt/barriers.
// A-frag: row=lane&31, k=(lane>>5)*8+e (half-wave-K, same pattern as the
// verified 16x16 mapping). C/D: col=lane&31, row=(r&3)+8*(r>>2)+4*(lane>>5)
// (guide m74/m101). TAU-recheck keeps labels = exact argmax regardless of
// the changed f32 summation order.
// ---------------------------------------------------------------------------
__global__ __launch_bounds__(256, 3)
void assign_kernel(const float* __restrict__ X,
                   const unsigned short* __restrict__ Pn,
                   const float* __restrict__ cnorm,
                   int* __restrict__ labels,
                   int* __restrict__ list,
                   int* __restrict__ counter) {
    __shared__ __align__(16) char lds[49664];  // 3x16KB B bufs + 512B cn slot

    const int tid = threadIdx.x;        // 0..255
    const int lane = tid & 63;
    const int wid = tid >> 6;           // 0..3
    const int wrow = wid >> 1;          // 0..1 (32-row half)
    const int wcol = wid & 1;           // 0..1 (64-col half per chunk)
    const int l31 = lane & 31;
    const int lh = lane >> 5;           // 0..1
    const int pbase = blockIdx.x * 64;
    const char* PnB = (const char*)Pn;

    // ---- stage A tile (64 rows x 128 k), split to bf16 h/l, XOR-swizzled ----
#pragma unroll
    for (int i = 0; i < 8; i++) {
        int f = i * 256 + tid;          // float4-slot over 64 rows x 32 slots
        int row = f >> 5, c4 = f & 31;
        float4 v = *(const float4*)&X[(size_t)(pbase + row) * D + c4 * 4];
        unsigned short h0 = f2bf(v.x), h1 = f2bf(v.y), h2 = f2bf(v.z), h3 = f2bf(v.w);
        unsigned short l0 = f2bf(v.x - bf2f(h0)), l1 = f2bf(v.y - bf2f(h1));
        unsigned short l2 = f2bf(v.z - bf2f(h2)), l3 = f2bf(v.w - bf2f(h3));
        uint2 ph = { (unsigned)h0 | ((unsigned)h1 << 16), (unsigned)h2 | ((unsigned)h3 << 16) };
        uint2 pl = { (unsigned)l0 | ((unsigned)l1 << 16), (unsigned)l2 | ((unsigned)l3 << 16) };
        int ad = (row * 256 + c4 * 8) ^ ((row & 7) << 4);
        *(uint2*)(lds + ad) = ph;
        *(uint2*)(lds + 16384 + ad) = pl;
    }
    __syncthreads();

    // ---- hoist a-frags: 8 ks16 x {h,l} = 16 bf16x8 = 64 VGPR ----
    // frag(ks16): lane -> row = wrow*32 + l31, k = ks16*16 + lh*8 + e
    bf16x8 rah[8], ral[8];
    {
        int row = wrow * 32 + l31;
        int sw = (row & 7) << 4;
#pragma unroll
        for (int ks16 = 0; ks16 < 8; ks16++) {
            int ad = (row * 256 + ks16 * 32 + lh * 16) ^ sw;
            rah[ks16] = *(const bf16x8*)(lds + ad);
            ral[ks16] = *(const bf16x8*)(lds + 16384 + ad);
        }
    }
    __syncthreads();   // A reads done; region becomes B buffers (drains all)

    float b1[16], b2[16];
    int i1[16];
#pragma unroll
    for (int s = 0; s < 16; s++) { b1[s] = -INFINITY; b2[s] = -INFINITY; i1[s] = 0x7fffffff; }

    // prologue: issue gll for step0 (ct0/ks0 -> buf0), step1 (ct0/ks1 -> buf1)
#pragma unroll
    for (int i = 0; i < 4; i++) {
        int seg = wid * 4 + i;
        GLL16(PnB + seg * 1024 + lane * 16, lds + seg * 1024);
    }
#pragma unroll
    for (int i = 0; i < 4; i++) {
        int seg = wid * 4 + i;
        GLL16(PnB + (size_t)(1 * 128) * 2048 + seg * 1024 + lane * 16,
              lds + 16384 + seg * 1024);
    }

    // STEP(KS): vmcnt(N) -> barrier -> issue gll(t+2) [+cn at ks0] -> 12 MFMA
#define STEP(KS, VMSTR) do {                                                  \
        asm volatile("s_waitcnt vmcnt(" VMSTR ")" ::: "memory");              \
        __builtin_amdgcn_s_barrier();                                         \
        asm volatile("" ::: "memory");                                        \
        __builtin_amdgcn_sched_barrier(0);                                    \
        int t_ = ct * 4 + (KS);                                               \
        int s2_ = t_ + 2;                                                     \
        int s2c_ = (s2_ > 63) ? 63 : s2_;                                     \
        char* bstage_ = lds + (unsigned)(s2_ % 3) * 16384;                    \
        const char* nsrc_ = PnB + ((size_t)((s2c_ & 3) * 128 + (s2c_ >> 2) * 8)) * 2048; \
        _Pragma("unroll")                                                     \
        for (int i_ = 0; i_ < 4; i_++) {                                      \
            int seg_ = wid * 4 + i_;                                          \
            GLL16(nsrc_ + seg_ * 1024 + lane * 16, bstage_ + seg_ * 1024);    \
        }                                                                     \
        if ((KS) == 0) {                                                      \
            const float* cs_ = cnorm + ct * 128;                              \
            GLL4(cs_ + lane, lds + CNOFF);                                    \
            GLL4(cs_ + 64 + lane, lds + CNOFF + 256);                         \
        }                                                                     \
        const char* bcur_ = lds + (unsigned)(t_ % 3) * 16384;                 \
        __builtin_amdgcn_s_setprio(1);                                        \
        _Pragma("unroll")                                                     \
        for (int sub_ = 0; sub_ < 2; sub_++) {                                \
            _Pragma("unroll")                                                 \
            for (int cj_ = 0; cj_ < 2; cj_++) {                               \
                int f_ = sub_ * 8 + (wcol * 2 + cj_) * 2;                     \
                bf16x8 bh_ = *(const bf16x8*)(bcur_ + f_ * 1024 + lane * 16); \
                bf16x8 bl_ = *(const bf16x8*)(bcur_ + f_ * 1024 + 1024 + lane * 16); \
                acc32[cj_] = __builtin_amdgcn_mfma_f32_32x32x16_bf16(rah[(KS) * 2 + sub_], bh_, acc32[cj_], 0, 0, 0); \
                acc32[cj_] = __builtin_amdgcn_mfma_f32_32x32x16_bf16(rah[(KS) * 2 + sub_], bl_, acc32[cj_], 0, 0, 0); \
                acc32[cj_] = __builtin_amdgcn_mfma_f32_32x32x16_bf16(ral[(KS) * 2 + sub_], bh_, acc32[cj_], 0, 0, 0); \
            }                                                                 \
        }                                                                     \
        __builtin_amdgcn_s_setprio(0);                                        \
    } while (0)

    for (int ct = 0; ct < KC / 128; ct++) {
        f32x16 acc32[2];
#pragma unroll
        for (int cj = 0; cj < 2; cj++)
#pragma unroll
            for (int r = 0; r < 16; r++) acc32[cj][r] = 0.f;

        STEP(0, "4");
        STEP(1, "6");
        STEP(2, "6");
        STEP(3, "4");

        // epilogue: cn from LDS slot; med3 branchless top-2.
        // lane holds col = ...+ l31; reg r -> row (r&3)+8*(r>>2)+4*lh.
        const float* cnL = (const float*)(lds + CNOFF);
#pragma unroll
        for (int cj = 0; cj < 2; cj++) {
            int col = ct * 128 + wcol * 64 + cj * 32 + l31;
            float cnv = cnL[wcol * 64 + cj * 32 + l31];
#pragma unroll
            for (int r = 0; r < 16; r++) {
                float sv = __builtin_fmaf(2.0f, acc32[cj][r], -cnv);
                float nb2 = __builtin_amdgcn_fmed3f(b1[r], b2[r], sv);
                bool gt1 = sv > b1[r];
                i1[r] = gt1 ? col : i1[r];
                b1[r] = fmaxf(b1[r], sv);
                b2[r] = nb2;
            }
        }
    }
#undef STEP

    // merge top-2 across the 32 l31 lanes of each half (branchless)
#pragma unroll
    for (int s = 0; s < 16; s++) {
#pragma unroll
        for (int m = 1; m < 32; m <<= 1) {
            float ob1 = __shfl_xor(b1[s], m, 64);
            int   oi  = __shfl_xor(i1[s], m, 64);
            float ob2 = __shfl_xor(b2[s], m, 64);
            bool gt = ob1 > b1[s];
            bool eq = ob1 == b1[s];
            float nb2 = gt ? fmaxf(b1[s], ob2) : fmaxf(b2[s], ob1);
            nb2 = eq ? b1[s] : nb2;
            int ni = gt ? oi : i1[s];
            ni = (eq && oi < i1[s]) ? oi : ni;
            b1[s] = gt ? ob1 : b1[s];
            b2[s] = nb2;
            i1[s] = ni;
        }
    }

    // cross-wave merge (wcol 0 vs 1) via LDS aliased onto buf0
    __syncthreads();                          // full drain (incl. tail dummies)
    float* mb1 = (float*)lds;                 // [2][64]
    float* mb2 = ((float*)lds) + 128;         // [2][64]
    int*   mi1 = (int*)(((float*)lds) + 256); // [2][64]
    if (l31 == 0) {
#pragma unroll
        for (int r = 0; r < 16; r++) {
            int row = wrow * 32 + (r & 3) + 8 * (r >> 2) + 4 * lh;
            mb1[wcol * 64 + row] = b1[r];
            mb2[wcol * 64 + row] = b2[r];
            mi1[wcol * 64 + row] = i1[r];
        }
    }
    __syncthreads();
    if (tid < 64) {
        float a1 = mb1[tid], a2 = mb2[tid];  int ai = mi1[tid];
        float c1 = mb1[64 + tid], c2 = mb2[64 + tid];  int ci = mi1[64 + tid];
        float best, second;  int bi;
        if (a1 > c1)      { best = a1; bi = ai; second = fmaxf(a2, c1); }
        else if (a1 < c1) { best = c1; bi = ci; second = fmaxf(c2, a1); }
        else              { best = a1; bi = (ai < ci) ? ai : ci; second = a1; }
        int p = pbase + tid;
        labels[p] = bi;
        if (best - second < TAU) {
            int idx = atomicAdd(counter, 1);
            list[idx] = p;
        }
    }
}

// ---------------------------------------------------------------------------
// recheck (per-point, proven): f64 exact argmax over all 2048 clusters.
// ---------------------------------------------------------------------------
__global__ void recheck_kernel(const float* __restrict__ X,
                               const double* __restrict__ CT64,
                               const double* __restrict__ cn64,
                               const int* __restrict__ list,
                               const int* __restrict__ counter,
                               int* __restrict__ labels) {
    __shared__ float xrow[D];
    __shared__ double rb[4];
    __shared__ int ri[4];
    int cnt = *counter;
    for (int ii = blockIdx.x; ii < cnt; ii += gridDim.x) {
        int p = list[ii];
        __syncthreads();
        if (threadIdx.x < D) xrow[threadIdx.x] = X[(size_t)p * D + threadIdx.x];
        __syncthreads();
        double xn = 0.0;
#pragma unroll 16
        for (int d = 0; d < D; d++) {
            double xv = (double)xrow[d];
            xn = fma(xv, xv, xn);
        }
        double best = -1.0e300;
        int bi = 0x7fffffff;
#pragma unroll
        for (int g = 0; g < 8; g++) {
            int c = threadIdx.x + 256 * g;
            double acc = 0.0;
#pragma unroll 16
            for (int d = 0; d < D; d++)
                acc = fma((double)xrow[d], CT64[(size_t)d * KC + c], acc);
            double s = 2.0 * acc - xn - cn64[c];
            if (s > best || (s == best && c < bi)) { best = s; bi = c; }
        }
#pragma unroll
        for (int m = 1; m < 64; m <<= 1) {
            double ob = __shfl_xor(best, m, 64);
            int oi = __shfl_xor(bi, m, 64);
            if (ob > best || (ob == best && oi < bi)) { best = ob; bi = oi; }
        }
        int w = threadIdx.x >> 6;
        if ((threadIdx.x & 63) == 0) { rb[w] = best; ri[w] = bi; }
        __syncthreads();
        if (threadIdx.x == 0) {
            double bb = rb[0]; int bbi = ri[0];
            for (int w2 = 1; w2 < 4; w2++)
                if (rb[w2] > bb || (rb[w2] == bb && ri[w2] < bbi)) { bb = rb[w2]; bbi = ri[w2]; }
            labels[p] = bbi;
        }
    }
}

// ---------------------------------------------------------------------------
// accum + fused update: ballot-gather over CG=8 clusters (deterministic),
// then in-block: v = sum/count, write C64/CT64/Pn/outC, cnorm, counter reset.
// ---------------------------------------------------------------------------
__global__ __launch_bounds__(512)
void accum_kernel(const float* __restrict__ X,
                  const int* __restrict__ labels,
                  double* __restrict__ C64, double* __restrict__ CT64,
                  unsigned short* __restrict__ Pn,
                  double* __restrict__ cn64, float* __restrict__ cn32,
                  int* __restrict__ counter,
                  float* __restrict__ outC) {
    __shared__ double sred[8][CG][64][2];   // 64 KB
    __shared__ int cred[8][CG];
    __shared__ int cntS[CG];
    __shared__ double cnp[2][8];
    const int lane = threadIdx.x & 63;
    const int w = threadIdx.x >> 6;         // 0..7
    const int kbase = blockIdx.x * CG;
    const int base0 = w * (NP / 8);
    double s0[CG], s1[CG];
    int cnt[CG];
#pragma unroll
    for (int c = 0; c < CG; c++) { s0[c] = 0.0; s1[c] = 0.0; cnt[c] = 0; }

    for (int it = 0; it < (NP / 8) / 256; it++) {      // 64 iters
        int4 lab = *(const int4*)&labels[base0 + it * 256 + lane * 4];
#pragma unroll
        for (int j = 0; j < 4; j++) {
            int lv = (j == 0) ? lab.x : (j == 1) ? lab.y : (j == 2) ? lab.z : lab.w;
            int rel = lv - kbase;
#pragma unroll
            for (int c = 0; c < CG; c++) {
                unsigned long long m = __ballot(rel == c);
                cnt[c] += __popcll(m);
                while (m) {
                    int b = __ffsll(m) - 1;
                    m &= m - 1;
                    int p = base0 + it * 256 + b * 4 + j;
                    float2 v = *(const float2*)&X[(size_t)p * D + lane * 2];
                    s0[c] += (double)v.x;
                    s1[c] += (double)v.y;
                }
            }
        }
    }
#pragma unroll
    for (int c = 0; c < CG; c++) {
        sred[w][c][lane][0] = s0[c];
        sred[w][c][lane][1] = s1[c];
    }
    if (lane < CG) cred[w][lane] = cnt[lane];
    __syncthreads();

    if (threadIdx.x < CG) {
        int s = 0;
#pragma unroll
        for (int ww = 0; ww < 8; ww++) s += cred[ww][threadIdx.x];
        cntS[threadIdx.x] = s;
    }
    __syncthreads();

#pragma unroll
    for (int rep = 0; rep < 2; rep++) {
        int idx = rep * 512 + threadIdx.x;      // 0..1023
        int c = idx >> 7, d = idx & 127;        // c in [rep*4, rep*4+4)
        double s = 0.0;
#pragma unroll
        for (int ww = 0; ww < 8; ww++) s += sred[ww][c][d >> 1][d & 1];
        int k = kbase + c;
        int n = cntS[c];
        double v = (n > 0) ? s / (double)n : 0.0;
        C64[(size_t)k * D + d] = v;
        CT64[(size_t)d * KC + k] = v;
        float vf = (float)v;
        unsigned short h = f2bf(vf);
        Pn[pslot(k, d, 0)] = h;
        Pn[pslot(k, d, 1)] = f2bf(vf - bf2f(h));
        if (outC) outC[(size_t)k * D + d] = vf;
        double sq = v * v;
#pragma unroll
        for (int m = 1; m < 64; m <<= 1) sq += __shfl_xor(sq, m, 64);
        if (lane == 0) cnp[rep][w] = sq;
    }
    __syncthreads();
    if (threadIdx.x < CG) {
        int c = threadIdx.x;
        int rep = c >> 2, wp = (c & 3) * 2;
        double cn = cnp[rep][wp] + cnp[rep][wp + 1];
        cn64[kbase + c] = cn;
        cn32[kbase + c] = (float)cn;
    }
    if (blockIdx.x == 0 && threadIdx.x == 0) *counter = 0;
}

__global__ void lab2f_kernel(const int* __restrict__ labels, float* __restrict__ out) {
    int t = blockIdx.x * 256 + threadIdx.x;
    out[t] = (float)labels[t];
}

extern "C" void kernel_launch(void* const* d_in, const int* in_sizes, int n_in,
                              void* d_out, int out_size, void* d_ws, size_t ws_size,
                              hipStream_t stream) {
    const float* X = (const float*)d_in[0];
    const float* initC = (const float*)d_in[1];
    float* out = (float*)d_out;

    char* w = (char*)d_ws;
    const size_t MB = 1u << 20;
    double* C64    = (double*)(w);                          // 2 MB
    double* CT64   = (double*)(w + 4 * MB);                 // 2 MB
    unsigned short* Pn = (unsigned short*)(w + 6 * MB);     // 1 MB (frag panel)
    int*    labels = (int*)   (w + 7 * MB);                 // 512 KB
    int*    list   = (int*)   (w + 7 * MB + 512 * 1024);    // 512 KB
    double* cn64   = (double*)(w + 8 * MB);                 // 16 KB
    float*  cn32   = (float*) (w + 8 * MB + 16 * 1024);     // 8 KB
    int*    counter= (int*)   (w + 8 * MB + 32 * 1024);     // 4 B

    init_kernel<<<(KC * D) / 256, 256, 0, stream>>>(initC, C64, CT64, Pn, cn64, cn32, counter);

    for (int it = 0; it < ITERS; it++) {
        assign_kernel<<<NP / 64, 256, 0, stream>>>(X, Pn, cn32, labels, list, counter);
        recheck_kernel<<<2048, 256, 0, stream>>>(X, CT64, cn64, list, counter, labels);
        accum_kernel<<<KC / CG, 512, 0, stream>>>(X, labels, C64, CT64, Pn, cn64, cn32,
                                                  counter, (it == ITERS - 1) ? out : nullptr);
    }
    lab2f_kernel<<<NP / 256, 256, 0, stream>>>(labels, out + (size_t)KC * D);
}

// Round 24
// 1830.978 us; speedup vs baseline: 1.1247x; 1.1247x over previous
//
#include <hip/hip_runtime.h>
#include <hip/hip_bf16.h>

#define NP 131072
#define D 128
#define KC 2048
#define ITERS 5
#define CG 8           // clusters per accum block

#define TAU 0.015f     // bf16x3 top-2 gap below which we recheck in f64
#define CNOFF 49152    // LDS byte offset of the 512B cnorm slot

#if defined(__has_builtin)
#if __has_builtin(__builtin_amdgcn_global_load_lds)
#define USE_GLL 1
#endif
#endif

typedef short bf16x8 __attribute__((ext_vector_type(8)));
typedef float f32x4 __attribute__((ext_vector_type(4)));

__device__ inline unsigned short f2bf(float x) {
    __hip_bfloat16 b = __float2bfloat16(x);
    return *reinterpret_cast<unsigned short*>(&b);
}
__device__ inline float bf2f(unsigned short u) {
    union { unsigned int i; float f; } c; c.i = ((unsigned int)u) << 16; return c.f;
}

// ks-major fragment panel: for cluster k, dim d:
//   g=k>>4, t15=k&15, ks=d>>5, q=(d>>3)&3, e=d&7, lane=q*16+t15
//   ushort idx = ((ks*128+g)*2 + hl)*512 + lane*8 + e
__device__ inline size_t pslot(int k, int d, int hl) {
    int g = k >> 4, t15 = k & 15, ks = d >> 5, q = (d >> 3) & 3, e = d & 7;
    return ((size_t)((ks * 128 + g) * 2 + hl)) * 512 + (q * 16 + t15) * 8 + e;
}

#if USE_GLL
#define GLL16(srcp, dstp) __builtin_amdgcn_global_load_lds( \
    (const __attribute__((address_space(1))) unsigned int*)(srcp), \
    (__attribute__((address_space(3))) unsigned int*)(dstp), 16, 0, 0)
#define GLL4(srcp, dstp) __builtin_amdgcn_global_load_lds( \
    (const __attribute__((address_space(1))) unsigned int*)(srcp), \
    (__attribute__((address_space(3))) unsigned int*)(dstp), 4, 0, 0)
#else
#define GLL16(srcp, dstp) do { *(uint4*)((char*)(dstp) + lane * 16) = *(const uint4*)(srcp); } while (0)
#define GLL4(srcp, dstp)  do { *(unsigned int*)((char*)(dstp) + lane * 4) = *(const unsigned int*)(srcp); } while (0)
#endif

// ---------------------------------------------------------------------------
// init: C64 / CT64 / panel + fused cnorm + counter reset for iteration 0
// ---------------------------------------------------------------------------
__global__ void init_kernel(const float* __restrict__ initC,
                            double* __restrict__ C64, double* __restrict__ CT64,
                            unsigned short* __restrict__ Pn,
                            double* __restrict__ cn64, float* __restrict__ cn32,
                            int* __restrict__ counter) {
    __shared__ double sred[4];
    int tid = threadIdx.x;
    int t = blockIdx.x * 256 + tid;       // 262144
    float v = initC[t];
    double dv = (double)v;
    C64[t] = dv;
    CT64[(size_t)(t & 127) * KC + (t >> 7)] = dv;
    unsigned short h = f2bf(v);
    int k = t >> 7, d = t & 127;
    Pn[pslot(k, d, 0)] = h;
    Pn[pslot(k, d, 1)] = f2bf(v - bf2f(h));
    double s = dv * dv;
#pragma unroll
    for (int m = 1; m < 64; m <<= 1) s += __shfl_xor(s, m, 64);
    if ((tid & 63) == 0) sred[tid >> 6] = s;
    __syncthreads();
    if (tid == 0)   { double ss = sred[0] + sred[1]; cn64[k] = ss; cn32[k] = (float)ss; }
    if (tid == 128) { double ss = sred[2] + sred[3]; cn64[k] = ss; cn32[k] = (float)ss; }
    if (blockIdx.x == 0 && tid == 0) *counter = 0;
}

// ---------------------------------------------------------------------------
// bf16x3 MFMA assign — R17's proven 4-wave/BM=64 counted-vmcnt pipeline
// + med3 branchless top-2 (R21/R22 best: ~203us, MfmaUtil 46%).
// ---------------------------------------------------------------------------
__global__ __launch_bounds__(256, 3)
void assign_kernel(const float* __restrict__ X,
                   const unsigned short* __restrict__ Pn,
                   const float* __restrict__ cnorm,
                   int* __restrict__ labels,
                   int* __restrict__ list,
                   int* __restrict__ counter) {
    __shared__ __align__(16) char lds[49664];  // 3x16KB B bufs + 512B cn slot

    const int tid = threadIdx.x;        // 0..255
    const int lane = tid & 63;
    const int wid = tid >> 6;           // 0..3
    const int wrow = wid >> 1;          // 0..1 (32-row half)
    const int wcol = wid & 1;           // 0..1 (64-col half per chunk)
    const int t15 = lane & 15;
    const int q = lane >> 4;            // 0..3
    const int pbase = blockIdx.x * 64;
    const char* PnB = (const char*)Pn;

    // ---- stage A tile (64 rows x 128 k), split to bf16 h/l, XOR-swizzled ----
#pragma unroll
    for (int i = 0; i < 8; i++) {
        int f = i * 256 + tid;          // float4-slot over 64 rows x 32 slots
        int row = f >> 5, c4 = f & 31;
        float4 v = *(const float4*)&X[(size_t)(pbase + row) * D + c4 * 4];
        unsigned short h0 = f2bf(v.x), h1 = f2bf(v.y), h2 = f2bf(v.z), h3 = f2bf(v.w);
        unsigned short l0 = f2bf(v.x - bf2f(h0)), l1 = f2bf(v.y - bf2f(h1));
        unsigned short l2 = f2bf(v.z - bf2f(h2)), l3 = f2bf(v.w - bf2f(h3));
        uint2 ph = { (unsigned)h0 | ((unsigned)h1 << 16), (unsigned)h2 | ((unsigned)h3 << 16) };
        uint2 pl = { (unsigned)l0 | ((unsigned)l1 << 16), (unsigned)l2 | ((unsigned)l3 << 16) };
        int ad = (row * 256 + c4 * 8) ^ ((row & 7) << 4);
        *(uint2*)(lds + ad) = ph;
        *(uint2*)(lds + 16384 + ad) = pl;
    }
    __syncthreads();

    // ---- hoist a-frags: rt=2 x ks=4 x {h,l} = 16 bf16x8 = 64 VGPR ----
    bf16x8 rah[2][4], ral[2][4];
#pragma unroll
    for (int rt = 0; rt < 2; rt++) {
        int row = wrow * 32 + rt * 16 + t15;
        int sw = (row & 7) << 4;
#pragma unroll
        for (int ks = 0; ks < 4; ks++) {
            int ad = (row * 256 + ks * 64 + q * 16) ^ sw;
            rah[rt][ks] = *(const bf16x8*)(lds + ad);
            ral[rt][ks] = *(const bf16x8*)(lds + 16384 + ad);
        }
    }
    __syncthreads();   // A reads done; region becomes B buffers (drains all)

    float b1[8], b2[8];
    int i1[8];
#pragma unroll
    for (int s = 0; s < 8; s++) { b1[s] = -INFINITY; b2[s] = -INFINITY; i1[s] = 0x7fffffff; }

    // prologue: issue gll for step0 (ct0/ks0 -> buf0), step1 (ct0/ks1 -> buf1)
#pragma unroll
    for (int i = 0; i < 4; i++) {
        int seg = wid * 4 + i;
        GLL16(PnB + seg * 1024 + lane * 16, lds + seg * 1024);
    }
#pragma unroll
    for (int i = 0; i < 4; i++) {
        int seg = wid * 4 + i;
        GLL16(PnB + (size_t)(1 * 128) * 2048 + seg * 1024 + lane * 16,
              lds + 16384 + seg * 1024);
    }

    // STEP(KS): vmcnt(N) -> barrier -> issue gll(t+2) [+cn at ks0] -> MFMA
#define STEP(KS, VMSTR) do {                                                  \
        asm volatile("s_waitcnt vmcnt(" VMSTR ")" ::: "memory");              \
        __builtin_amdgcn_s_barrier();                                         \
        asm volatile("" ::: "memory");                                        \
        __builtin_amdgcn_sched_barrier(0);                                    \
        int t_ = ct * 4 + (KS);                                               \
        int s2_ = t_ + 2;                                                     \
        int s2c_ = (s2_ > 63) ? 63 : s2_;                                     \
        char* bstage_ = lds + (unsigned)(s2_ % 3) * 16384;                    \
        const char* nsrc_ = PnB + ((size_t)((s2c_ & 3) * 128 + (s2c_ >> 2) * 8)) * 2048; \
        _Pragma("unroll")                                                     \
        for (int i_ = 0; i_ < 4; i_++) {                                      \
            int seg_ = wid * 4 + i_;                                          \
            GLL16(nsrc_ + seg_ * 1024 + lane * 16, bstage_ + seg_ * 1024);    \
        }                                                                     \
        if ((KS) == 0) {                                                      \
            const float* cs_ = cnorm + ct * 128;                              \
            GLL4(cs_ + lane, lds + CNOFF);                                    \
            GLL4(cs_ + 64 + lane, lds + CNOFF + 256);                         \
        }                                                                     \
        const char* bcur_ = lds + (unsigned)(t_ % 3) * 16384;                 \
        __builtin_amdgcn_s_setprio(1);                                        \
        _Pragma("unroll")                                                     \
        for (int cj_ = 0; cj_ < 4; cj_++) {                                   \
            int gl_ = wcol * 4 + cj_;                                         \
            bf16x8 bh_ = *(const bf16x8*)(bcur_ + gl_ * 2048 + lane * 16);    \
            bf16x8 bl_ = *(const bf16x8*)(bcur_ + gl_ * 2048 + 1024 + lane * 16); \
            _Pragma("unroll")                                                 \
            for (int rt_ = 0; rt_ < 2; rt_++) {                               \
                acc[rt_][cj_] = __builtin_amdgcn_mfma_f32_16x16x32_bf16(rah[rt_][KS], bh_, acc[rt_][cj_], 0, 0, 0); \
                acc[rt_][cj_] = __builtin_amdgcn_mfma_f32_16x16x32_bf16(rah[rt_][KS], bl_, acc[rt_][cj_], 0, 0, 0); \
                acc[rt_][cj_] = __builtin_amdgcn_mfma_f32_16x16x32_bf16(ral[rt_][KS], bh_, acc[rt_][cj_], 0, 0, 0); \
            }                                                                 \
        }                                                                     \
        __builtin_amdgcn_s_setprio(0);                                        \
    } while (0)

    for (int ct = 0; ct < KC / 128; ct++) {
        f32x4 acc[2][4];
#pragma unroll
        for (int rt = 0; rt < 2; rt++)
#pragma unroll
            for (int cj = 0; cj < 4; cj++) acc[rt][cj] = (f32x4){0.f, 0.f, 0.f, 0.f};

        STEP(0, "4");
        STEP(1, "6");
        STEP(2, "6");
        STEP(3, "4");

        // epilogue: cn from LDS slot; med3 branchless top-2
        const float* cnL = (const float*)(lds + CNOFF);
#pragma unroll
        for (int cj = 0; cj < 4; cj++) {
            int col = ct * 128 + wcol * 64 + cj * 16 + t15;
            float cnv = cnL[wcol * 64 + cj * 16 + t15];
#pragma unroll
            for (int rt = 0; rt < 2; rt++)
#pragma unroll
                for (int rg = 0; rg < 4; rg++) {
                    int s = rt * 4 + rg;
                    float sv = __builtin_fmaf(2.0f, acc[rt][cj][rg], -cnv);
                    float nb2 = __builtin_amdgcn_fmed3f(b1[s], b2[s], sv);
                    bool gt1 = sv > b1[s];
                    i1[s] = gt1 ? col : i1[s];
                    b1[s] = fmaxf(b1[s], sv);
                    b2[s] = nb2;
                }
        }
    }
#undef STEP

    // merge top-2 across the 16 t15 lanes of each q-group (branchless)
#pragma unroll
    for (int s = 0; s < 8; s++) {
#pragma unroll
        for (int m = 1; m < 16; m <<= 1) {
            float ob1 = __shfl_xor(b1[s], m, 64);
            int   oi  = __shfl_xor(i1[s], m, 64);
            float ob2 = __shfl_xor(b2[s], m, 64);
            bool gt = ob1 > b1[s];
            bool eq = ob1 == b1[s];
            float nb2 = gt ? fmaxf(b1[s], ob2) : fmaxf(b2[s], ob1);
            nb2 = eq ? b1[s] : nb2;
            int ni = gt ? oi : i1[s];
            ni = (eq && oi < i1[s]) ? oi : ni;
            b1[s] = gt ? ob1 : b1[s];
            b2[s] = nb2;
            i1[s] = ni;
        }
    }

    // cross-wave merge (wcol 0 vs 1) via LDS aliased onto buf0
    __syncthreads();                          // full drain (incl. tail dummies)
    float* mb1 = (float*)lds;                 // [2][64]
    float* mb2 = ((float*)lds) + 128;         // [2][64]
    int*   mi1 = (int*)(((float*)lds) + 256); // [2][64]
    if (t15 == 0) {
#pragma unroll
        for (int rt = 0; rt < 2; rt++)
#pragma unroll
            for (int rg = 0; rg < 4; rg++) {
                int s = rt * 4 + rg;
                int row = wrow * 32 + rt * 16 + q * 4 + rg;
                mb1[wcol * 64 + row] = b1[s];
                mb2[wcol * 64 + row] = b2[s];
                mi1[wcol * 64 + row] = i1[s];
            }
    }
    __syncthreads();
    if (tid < 64) {
        float a1 = mb1[tid], a2 = mb2[tid];  int ai = mi1[tid];
        float c1 = mb1[64 + tid], c2 = mb2[64 + tid];  int ci = mi1[64 + tid];
        float best, second;  int bi;
        if (a1 > c1)      { best = a1; bi = ai; second = fmaxf(a2, c1); }
        else if (a1 < c1) { best = c1; bi = ci; second = fmaxf(c2, a1); }
        else              { best = a1; bi = (ai < ci) ? ai : ci; second = a1; }
        int p = pbase + tid;
        labels[p] = bi;
        if (best - second < TAU) {
            int idx = atomicAdd(counter, 1);
            list[idx] = p;
        }
    }
}

// ---------------------------------------------------------------------------
// recheck (per-point, PROVEN): f64 exact argmax over all 2048 clusters.
// ---------------------------------------------------------------------------
__global__ void recheck_kernel(const float* __restrict__ X,
                               const double* __restrict__ CT64,
                               const double* __restrict__ cn64,
                               const int* __restrict__ list,
                               const int* __restrict__ counter,
                               int* __restrict__ labels) {
    __shared__ float xrow[D];
    __shared__ double rb[4];
    __shared__ int ri[4];
    int cnt = *counter;
    for (int ii = blockIdx.x; ii < cnt; ii += gridDim.x) {
        int p = list[ii];
        __syncthreads();
        if (threadIdx.x < D) xrow[threadIdx.x] = X[(size_t)p * D + threadIdx.x];
        __syncthreads();
        double xn = 0.0;
#pragma unroll 16
        for (int d = 0; d < D; d++) {
            double xv = (double)xrow[d];
            xn = fma(xv, xv, xn);
        }
        double best = -1.0e300;
        int bi = 0x7fffffff;
#pragma unroll
        for (int g = 0; g < 8; g++) {
            int c = threadIdx.x + 256 * g;
            double acc = 0.0;
#pragma unroll 16
            for (int d = 0; d < D; d++)
                acc = fma((double)xrow[d], CT64[(size_t)d * KC + c], acc);
            double s = 2.0 * acc - xn - cn64[c];
            if (s > best || (s == best && c < bi)) { best = s; bi = c; }
        }
#pragma unroll
        for (int m = 1; m < 64; m <<= 1) {
            double ob = __shfl_xor(best, m, 64);
            int oi = __shfl_xor(bi, m, 64);
            if (ob > best || (ob == best && oi < bi)) { best = ob; bi = oi; }
        }
        int w = threadIdx.x >> 6;
        if ((threadIdx.x & 63) == 0) { rb[w] = best; ri[w] = bi; }
        __syncthreads();
        if (threadIdx.x == 0) {
            double bb = rb[0]; int bbi = ri[0];
            for (int w2 = 1; w2 < 4; w2++)
                if (rb[w2] > bb || (rb[w2] == bb && ri[w2] < bbi)) { bb = rb[w2]; bbi = ri[w2]; }
            labels[p] = bbi;
        }
    }
}

// ---------------------------------------------------------------------------
// accum + fused update: ballot-gather over CG=8 clusters (deterministic),
// then in-block: v = sum/count, write C64/CT64/Pn/outC, cnorm, counter reset.
// ---------------------------------------------------------------------------
__global__ __launch_bounds__(512)
void accum_kernel(const float* __restrict__ X,
                  const int* __restrict__ labels,
                  double* __restrict__ C64, double* __restrict__ CT64,
                  unsigned short* __restrict__ Pn,
                  double* __restrict__ cn64, float* __restrict__ cn32,
                  int* __restrict__ counter,
                  float* __restrict__ outC) {
    __shared__ double sred[8][CG][64][2];   // 64 KB
    __shared__ int cred[8][CG];
    __shared__ int cntS[CG];
    __shared__ double cnp[2][8];
    const int lane = threadIdx.x & 63;
    const int w = threadIdx.x >> 6;         // 0..7
    const int kbase = blockIdx.x * CG;
    const int base0 = w * (NP / 8);
    double s0[CG], s1[CG];
    int cnt[CG];
#pragma unroll
    for (int c = 0; c < CG; c++) { s0[c] = 0.0; s1[c] = 0.0; cnt[c] = 0; }

    for (int it = 0; it < (NP / 8) / 256; it++) {      // 64 iters
        int4 lab = *(const int4*)&labels[base0 + it * 256 + lane * 4];
#pragma unroll
        for (int j = 0; j < 4; j++) {
            int lv = (j == 0) ? lab.x : (j == 1) ? lab.y : (j == 2) ? lab.z : lab.w;
            int rel = lv - kbase;
#pragma unroll
            for (int c = 0; c < CG; c++) {
                unsigned long long m = __ballot(rel == c);
                cnt[c] += __popcll(m);
                while (m) {
                    int b = __ffsll(m) - 1;
                    m &= m - 1;
                    int p = base0 + it * 256 + b * 4 + j;
                    float2 v = *(const float2*)&X[(size_t)p * D + lane * 2];
                    s0[c] += (double)v.x;
                    s1[c] += (double)v.y;
                }
            }
        }
    }
#pragma unroll
    for (int c = 0; c < CG; c++) {
        sred[w][c][lane][0] = s0[c];
        sred[w][c][lane][1] = s1[c];
    }
    if (lane < CG) cred[w][lane] = cnt[lane];
    __syncthreads();

    if (threadIdx.x < CG) {
        int s = 0;
#pragma unroll
        for (int ww = 0; ww < 8; ww++) s += cred[ww][threadIdx.x];
        cntS[threadIdx.x] = s;
    }
    __syncthreads();

#pragma unroll
    for (int rep = 0; rep < 2; rep++) {
        int idx = rep * 512 + threadIdx.x;      // 0..1023
        int c = idx >> 7, d = idx & 127;        // c in [rep*4, rep*4+4)
        double s = 0.0;
#pragma unroll
        for (int ww = 0; ww < 8; ww++) s += sred[ww][c][d >> 1][d & 1];
        int k = kbase + c;
        int n = cntS[c];
        double v = (n > 0) ? s / (double)n : 0.0;
        C64[(size_t)k * D + d] = v;
        CT64[(size_t)d * KC + k] = v;
        float vf = (float)v;
        unsigned short h = f2bf(vf);
        Pn[pslot(k, d, 0)] = h;
        Pn[pslot(k, d, 1)] = f2bf(vf - bf2f(h));
        if (outC) outC[(size_t)k * D + d] = vf;
        double sq = v * v;
#pragma unroll
        for (int m = 1; m < 64; m <<= 1) sq += __shfl_xor(sq, m, 64);
        if (lane == 0) cnp[rep][w] = sq;
    }
    __syncthreads();
    if (threadIdx.x < CG) {
        int c = threadIdx.x;
        int rep = c >> 2, wp = (c & 3) * 2;
        double cn = cnp[rep][wp] + cnp[rep][wp + 1];
        cn64[kbase + c] = cn;
        cn32[kbase + c] = (float)cn;
    }
    if (blockIdx.x == 0 && threadIdx.x == 0) *counter = 0;
}

__global__ void lab2f_kernel(const int* __restrict__ labels, float* __restrict__ out) {
    int t = blockIdx.x * 256 + threadIdx.x;
    out[t] = (float)labels[t];
}

extern "C" void kernel_launch(void* const* d_in, const int* in_sizes, int n_in,
                              void* d_out, int out_size, void* d_ws, size_t ws_size,
                              hipStream_t stream) {
    const float* X = (const float*)d_in[0];
    const float* initC = (const float*)d_in[1];
    float* out = (float*)d_out;

    char* w = (char*)d_ws;
    const size_t MB = 1u << 20;
    double* C64    = (double*)(w);                          // 2 MB
    double* CT64   = (double*)(w + 4 * MB);                 // 2 MB
    unsigned short* Pn = (unsigned short*)(w + 6 * MB);     // 1 MB (ks-major panel)
    int*    labels = (int*)   (w + 7 * MB);                 // 512 KB
    int*    list   = (int*)   (w + 7 * MB + 512 * 1024);    // 512 KB
    double* cn64   = (double*)(w + 8 * MB);                 // 16 KB
    float*  cn32   = (float*) (w + 8 * MB + 16 * 1024);     // 8 KB
    int*    counter= (int*)   (w + 8 * MB + 32 * 1024);     // 4 B

    init_kernel<<<(KC * D) / 256, 256, 0, stream>>>(initC, C64, CT64, Pn, cn64, cn32, counter);

    for (int it = 0; it < ITERS; it++) {
        assign_kernel<<<NP / 64, 256, 0, stream>>>(X, Pn, cn32, labels, list, counter);
        recheck_kernel<<<2048, 256, 0, stream>>>(X, CT64, cn64, list, counter, labels);
        accum_kernel<<<KC / CG, 512, 0, stream>>>(X, labels, C64, CT64, Pn, cn64, cn32,
                                                  counter, (it == ITERS - 1) ? out : nullptr);
    }
    lab2f_kernel<<<NP / 256, 256, 0, stream>>>(labels, out + (size_t)KC * D);
}